// Round 9
// baseline (221.599 us; speedup 1.0000x reference)
//
#include <hip/hip_runtime.h>

#define BETA_F   1e-7f
#define LAMBDA_F 1e-8f

// problem sizes
#define HWSZ 262144      // 512*512
#define NBC  84          // NB*CO
#define NPIX 1024        // 32*32

// ws layout in floats
#define OFF_FO    0                         // 84*1024 = 86016
#define OFF_GSUM  86016                     // 4*1024*32 = 131072
#define OFF_INVN  (86016 + 131072)          // 217088, 4096 floats
#define OFF_RMAX  (217088 + 4096)           // 221184, 4096 floats
#define OFF_LS    (221184 + 4096)           // 225280, 84*7*8 = 4704 (8 slots/val)
#define OFF_ACC   (225280 + 4704)           // 229984, 4
#define ZERO_START OFF_RMAX
#define ZERO_COUNT (4096 + 4704 + 4)        // 8804

#define N_GRAM_BLK 144                      // 4 batches * 36 upper-tri tiles
#define N_LS_BLK   1024                     // 4 b * 256 slices of 1024 px

// upper-triangle tile lookup (rt <= ct)
__device__ const unsigned char RT_[36] =
    {0,0,0,0,0,0,0,0, 1,1,1,1,1,1,1, 2,2,2,2,2,2, 3,3,3,3,3, 4,4,4,4, 5,5,5, 6,6, 7};
__device__ const unsigned char CT_[36] =
    {0,1,2,3,4,5,6,7, 1,2,3,4,5,6,7, 2,3,4,5,6,7, 3,4,5,6,7, 4,5,6,7, 5,6,7, 6,7, 7};

// ================= prep: zero | resize | norm (block-range specialized) ======
__global__ __launch_bounds__(256) void k_prep(const float* __restrict__ fo_in,
                                              const float* __restrict__ fsem,
                                              float* __restrict__ ws) {
    const int bid = blockIdx.x, tid = threadIdx.x;
    if (bid < 35) {
        int i = bid * 256 + tid;
        if (i < ZERO_COUNT) ws[ZERO_START + i] = 0.f;
    } else if (bid < 119) {
        const int bc = bid - 35;
        const float* im = fo_in + bc * 4096;
        for (int p = tid; p < 1024; p += 256) {
            const int oy = p >> 5, ox = p & 31;
            const float R = 63.0f / 31.0f;      // same f32 arithmetic as JAX ref
            float sy = oy * R, sx = ox * R;
            int y0 = (int)sy, x0 = (int)sx;
            int y1 = min(y0 + 1, 63), x1 = min(x0 + 1, 63);
            float wy = sy - (float)y0, wx = sx - (float)x0;
            float v00 = im[y0 * 64 + x0], v01 = im[y0 * 64 + x1];
            float v10 = im[y1 * 64 + x0], v11 = im[y1 * 64 + x1];
            float top = v00 * (1.f - wx) + v01 * wx;
            float bot = v10 * (1.f - wx) + v11 * wx;
            ws[OFF_FO + bc * NPIX + p] = top * (1.f - wy) + bot * wy;
        }
    } else {
        const int blk = bid - 119;
        const int b = blk >> 4, pg = blk & 15;
        const int p0 = pg * 64;
        const int pi = tid & 63, cg = tid >> 6;
        float s = 0.f;
        for (int c = cg; c < 256; c += 4) {
            float v = fsem[(b * 256 + c) * 1024 + p0 + pi];
            s += v * v;
        }
        __shared__ float red[4][64];
        red[cg][pi] = s;
        __syncthreads();
        if (tid < 64) {
            float t = red[0][tid] + red[1][tid] + red[2][tid] + red[3][tid];
            ws[OFF_INVN + b * 1024 + p0 + tid] = 1.f / fmaxf(sqrtf(t), 1e-12f);
        }
    }
}

// ================= main: symmetric gram || levelset (unique-read) ============
// blocks [0,144): gram upper-tri 128x128 tiles (BK=16);
// blocks [144,1168): levelset, 1024-px slices. Target staged ONCE in LDS,
// o-channel stream reads every HBM byte exactly once -> logical traffic
// 344 MB -> 100 MB (read-path ceiling ~5.7 TB/s was the R6/R8 limit).
__device__ __forceinline__ int swz(int p4, int k) {
    int s = (p4 >> 1) | ((p4 & 1) << 4);   // rotate: parity bit to bit4
    return s ^ (k & 7);
}

__device__ __forceinline__ void acc_px(float4 o, float4 ta, float4 tb, float4 tc,
                                       float& dn, float& n0, float& n1, float& n2,
                                       float& q0, float& q1, float& q2) {
    dn += o.x + o.y + o.z + o.w;
    n0 += ta.x*o.x + ta.y*o.y + ta.z*o.z + ta.w*o.w;
    q0 += ta.x*ta.x*o.x + ta.y*ta.y*o.y + ta.z*ta.z*o.z + ta.w*ta.w*o.w;
    n1 += tb.x*o.x + tb.y*o.y + tb.z*o.z + tb.w*o.w;
    q1 += tb.x*tb.x*o.x + tb.y*tb.y*o.y + tb.z*tb.z*o.z + tb.w*tb.w*o.w;
    n2 += tc.x*o.x + tc.y*o.y + tc.z*o.z + tc.w*o.w;
    q2 += tc.x*tc.x*o.x + tc.y*tc.y*o.y + tc.z*tc.z*o.z + tc.w*tc.w*o.w;
}

__global__ __launch_bounds__(256) void k_main(const float* __restrict__ outp,
                                              const float* __restrict__ tgt,
                                              const float* __restrict__ fsem,
                                              float* __restrict__ ws) {
    __shared__ __align__(16) char smem[21504];
    const int tid = threadIdx.x;

    if (blockIdx.x < N_GRAM_BLK) {
        // ---------------- gram tile (rt<=ct): row-side + mirrored col-side ---
        float4* As4    = (float4*)smem;              // 8192 B  [16][32] f4
        float4* Bs4    = (float4*)(smem + 8192);     // 8192 B
        float*  gs_row = (float*)(smem + 16384);     // 2048 B  [128][4]
        float*  gs_col = (float*)(smem + 18432);     // 2048 B
        int*    rm_row = (int*)(smem + 20480);       // 512 B
        int*    rm_col = (int*)(smem + 20992);       // 512 B
        const int bid = blockIdx.x;
        const int b = bid / 36, t = bid % 36;
        const int rt = RT_[t], ct = CT_[t];
        const bool diag = (rt == ct);
        const int r0 = rt * 128, c0 = ct * 128;
        for (int i = tid; i < 512; i += 256) { gs_row[i] = 0.f; gs_col[i] = 0.f; }
        if (tid < 128) { rm_row[tid] = 0; rm_col[tid] = 0; }

        const int tr = tid >> 4, tc = tid & 15;
        float acc[8][8];
        #pragma unroll
        for (int i = 0; i < 8; ++i)
            #pragma unroll
            for (int j = 0; j < 8; ++j) acc[i][j] = 0.f;

        const int kl = tid >> 5, p4s = tid & 31;
        for (int kk = 0; kk < 16; ++kk) {
            __syncthreads();
            #pragma unroll
            for (int q = 0; q < 2; ++q) {
                int k = kl + q * 8;
                const float* srcA = &fsem[(b * 256 + kk * 16 + k) * 1024 + r0 + p4s * 4];
                const float* srcB = &fsem[(b * 256 + kk * 16 + k) * 1024 + c0 + p4s * 4];
                float4 va = *(const float4*)srcA;
                float4 vb = *(const float4*)srcB;
                int sl = swz(p4s, k);
                As4[k * 32 + sl] = va;
                Bs4[k * 32 + sl] = vb;
            }
            __syncthreads();
            #pragma unroll 4
            for (int k = 0; k < 16; ++k) {
                int k7 = k & 7;
                float4 a0 = As4[k * 32 + (tr ^ k7)];
                float4 a1 = As4[k * 32 + ((tr ^ k7) | 16)];
                float4 b0 = Bs4[k * 32 + (tc ^ k7)];
                float4 b1 = Bs4[k * 32 + ((tc ^ k7) | 16)];
                float a[8]  = {a0.x, a0.y, a0.z, a0.w, a1.x, a1.y, a1.z, a1.w};
                float bb[8] = {b0.x, b0.y, b0.z, b0.w, b1.x, b1.y, b1.z, b1.w};
                #pragma unroll
                for (int i = 0; i < 8; ++i)
                    #pragma unroll
                    for (int j = 0; j < 8; ++j)
                        acc[i][j] += a[i] * bb[j];
            }
        }

        float ir[8], ic[8];
        #pragma unroll
        for (int i = 0; i < 8; ++i) {
            ir[i] = ws[OFF_INVN + b * 1024 + r0 + tr * 8 + i];
            ic[i] = ws[OFF_INVN + b * 1024 + c0 + tc * 8 + i];
        }
        // row-side: rows r0+row, col-groups in ct-range
        const int gr = tc >> 2;   // thread's 8 cols stay in one 32-col group
        #pragma unroll
        for (int i = 0; i < 8; ++i) {
            float s = 0.f, m = 0.f;
            #pragma unroll
            for (int j = 0; j < 8; ++j) {
                float v = fmaxf(acc[i][j], 0.f) * ir[i] * ic[j];
                s += v;
                m = fmaxf(m, v);
            }
            int row = tr * 8 + i;
            atomicAdd(&gs_row[row * 4 + gr], s);
            atomicMax(&rm_row[row], __float_as_int(m));
        }
        // col-side (mirror, rt<ct only): rows c0+col, col-groups in rt-range
        if (!diag) {
            const int gc = tr >> 2;  // thread's 8 rows stay in one 32-row group
            #pragma unroll
            for (int j = 0; j < 8; ++j) {
                float s = 0.f, m = 0.f;
                #pragma unroll
                for (int i = 0; i < 8; ++i) {
                    float v = fmaxf(acc[i][j], 0.f) * ir[i] * ic[j];
                    s += v;
                    m = fmaxf(m, v);
                }
                int col = tc * 8 + j;
                atomicAdd(&gs_col[col * 4 + gc], s);
                atomicMax(&rm_col[col], __float_as_int(m));
            }
        }
        __syncthreads();
        for (int i = tid; i < 512; i += 256) {
            int row = i >> 2, gg = i & 3;
            ws[OFF_GSUM + (b * 1024 + r0 + row) * 32 + ct * 4 + gg] = gs_row[i];
            if (!diag)
                ws[OFF_GSUM + (b * 1024 + c0 + row) * 32 + rt * 4 + gg] = gs_col[i];
        }
        if (tid < 128) {
            atomicMax((int*)&ws[OFF_RMAX + b * 1024 + r0 + tid], rm_row[tid]);
            if (!diag)
                atomicMax((int*)&ws[OFF_RMAX + b * 1024 + c0 + tid], rm_col[tid]);
        }
    } else {
        // -------- levelset, unique-read: target in LDS, per-wave channels ----
        float* tls = (float*)smem;                   // [3][1024] = 12 KB
        const int blk = blockIdx.x - N_GRAM_BLK;     // 0..1023
        const int b = blk >> 8, s = blk & 255;
        const size_t tbase = (size_t)b * (3 * HWSZ) + s * 1024 + tid * 4;
        #pragma unroll
        for (int ch = 0; ch < 3; ++ch) {
            float4 tv = *(const float4*)(tgt + tbase + (size_t)ch * HWSZ);
            *(float4*)(tls + ch * 1024 + tid * 4) = tv;
        }
        __syncthreads();
        const int w = tid >> 6, lane = tid & 63;
        for (int c = w; c < 21; c += 4) {      // wave-private channel set
            const float* obase = outp + (size_t)(b * 21 + c) * HWSZ + s * 1024;
            float4 o[4], t0[4], t1[4], t2[4];
            #pragma unroll
            for (int i = 0; i < 4; ++i)        // 4 loads in flight
                o[i] = *(const float4*)(obase + i * 256 + lane * 4);
            #pragma unroll
            for (int i = 0; i < 4; ++i) {
                const int p = i * 256 + lane * 4;
                t0[i] = *(const float4*)(tls + p);
                t1[i] = *(const float4*)(tls + 1024 + p);
                t2[i] = *(const float4*)(tls + 2048 + p);
            }
            float dn = 0, n0 = 0, n1 = 0, n2 = 0, q0 = 0, q1 = 0, q2 = 0;
            #pragma unroll
            for (int i = 0; i < 4; ++i)
                acc_px(o[i], t0[i], t1[i], t2[i], dn, n0, n1, n2, q0, q1, q2);
            float vals[7] = {n0, n1, n2, q0, q1, q2, dn};
            float myv = 0.f;
            #pragma unroll
            for (int q = 0; q < 7; ++q) {      // one butterfly per channel
                float v = vals[q];
                #pragma unroll
                for (int off = 32; off; off >>= 1) v += __shfl_xor(v, off);
                if (lane == q) myv = v;        // static-index capture (rule #20)
            }
            if (lane < 7)                      // 8-slot stride: 32-deep chains
                atomicAdd(&ws[OFF_LS + (b * 21 + c) * 56 + lane * 8 + (s & 7)], myv);
        }
    }
}

// ================= final TV contraction: sum A[b,c,r,k]*t[b,r,k] =============
__global__ __launch_bounds__(256) void k_tv(const float* __restrict__ ws,
                                            float* __restrict__ acc_out) {
    const int bc = blockIdx.y;
    const int b = bc / 21;
    const int tid = threadIdx.x;
    __shared__ float4 fo4[256];
    const float4* src = (const float4*)(ws + OFF_FO + bc * NPIX);
    fo4[tid] = src[tid];
    __syncthreads();
    const int r = blockIdx.x * 256 + tid;
    const float v = ((const float*)fo4)[r];
    float ak[32];
    #pragma unroll
    for (int k = 0; k < 32; ++k) ak[k] = 0.f;
    #pragma unroll 4
    for (int h = 0; h < 32; ++h) {
        #pragma unroll
        for (int k4 = 0; k4 < 8; ++k4) {
            float4 f = fo4[h * 8 + k4];
            ak[k4 * 4 + 0] += fabsf(v - f.x);
            ak[k4 * 4 + 1] += fabsf(v - f.y);
            ak[k4 * 4 + 2] += fabsf(v - f.z);
            ak[k4 * 4 + 3] += fabsf(v - f.w);
        }
    }
    const float rm = ws[OFF_RMAX + b * 1024 + r];
    const float inv = 1.f / (rm + 1e-5f);
    const float* t = ws + OFF_GSUM + (b * 1024 + r) * 32;
    float dot = 0.f;
    #pragma unroll
    for (int k = 0; k < 32; ++k) dot += ak[k] * t[k];
    float part = dot * inv;
    #pragma unroll
    for (int off = 32; off; off >>= 1) part += __shfl_xor(part, off);
    __shared__ float red[4];
    if ((tid & 63) == 0) red[tid >> 6] = part;
    __syncthreads();
    if (tid == 0) atomicAdd(acc_out, red[0] + red[1] + red[2] + red[3]);
}

// ================= combine to 3 outputs ======================================
__global__ void k_combine(const float* __restrict__ ws, float* __restrict__ out) {
    const int tid = threadIdx.x;   // 128
    float v = 0.f;
    if (tid < NBC) {
        const float* p = ws + OFF_LS + tid * 56;   // [7 vals][8 slots]
        float vv[7];
        #pragma unroll
        for (int q = 0; q < 7; ++q) {
            float s = 0.f;
            #pragma unroll
            for (int k = 0; k < 8; ++k) s += p[q * 8 + k];
            vv[q] = s;
        }
        float den = vv[6];
        v = (vv[3] + vv[4] + vv[5]) - (vv[0]*vv[0] + vv[1]*vv[1] + vv[2]*vv[2]) / den;
    }
    #pragma unroll
    for (int off = 32; off; off >>= 1) v += __shfl_xor(v, off);
    __shared__ float red[2];
    if ((tid & 63) == 0) red[tid >> 6] = v;
    __syncthreads();
    if (tid == 0) {
        float lsv = (red[0] + red[1]) * 0.25f;     // / B
        float tvv = ws[OFF_ACC] * 0.25f;           // / B
        out[0] = lsv * BETA_F;
        out[1] = tvv * LAMBDA_F * BETA_F;
        out[2] = (lsv + tvv * LAMBDA_F) * BETA_F;
    }
}

extern "C" void kernel_launch(void* const* d_in, const int* in_sizes, int n_in,
                              void* d_out, int out_size, void* d_ws, size_t ws_size,
                              hipStream_t stream) {
    const float* output   = (const float*)d_in[0];   // (4,21,512,512)
    const float* target   = (const float*)d_in[1];   // (4,3,512,512)
    const float* f_sem    = (const float*)d_in[2];   // (4,256,32,32)
    const float* f_output = (const float*)d_in[3];   // (4,21,64,64)
    // d_in[4] = use_NonLocal_TV, fixed to 1 by setup_inputs
    float* ws  = (float*)d_ws;
    float* out = (float*)d_out;

    hipLaunchKernelGGL(k_prep,    dim3(183),               dim3(256), 0, stream, f_output, f_sem, ws);
    hipLaunchKernelGGL(k_main,    dim3(N_GRAM_BLK+N_LS_BLK), dim3(256), 0, stream, output, target, f_sem, ws);
    hipLaunchKernelGGL(k_tv,      dim3(4, 84),             dim3(256), 0, stream, ws, ws + OFF_ACC);
    hipLaunchKernelGGL(k_combine, dim3(1),                 dim3(128), 0, stream, ws, out);
}

// Round 10
// 198.883 us; speedup vs baseline: 1.1142x; 1.1142x over previous
//
#include <hip/hip_runtime.h>

#define BETA_F   1e-7f
#define LAMBDA_F 1e-8f

// problem sizes
#define HWSZ 262144      // 512*512
#define NBC  84          // NB*CO
#define NPIX 1024        // 32*32

// ws layout in floats
#define OFF_FO    0                         // 84*1024 = 86016
#define OFF_GSUM  86016                     // 4*1024*32 = 131072
#define OFF_INVN  (86016 + 131072)          // 217088, 4096 floats
#define OFF_RMAX  (217088 + 4096)           // 221184, 4096 floats
#define OFF_LS    (221184 + 4096)           // 225280, 84*7 = 588
#define OFF_ACC   (225280 + 588)            // 225868, 4
#define ZERO_START OFF_RMAX
#define ZERO_COUNT (4096 + 588 + 4)         // 4688

#define N_GRAM_BLK 144                      // 4 batches * 36 upper-tri tiles

typedef __attribute__((ext_vector_type(8))) short short8;   // 8 bf16 (4 VGPR)
typedef __attribute__((ext_vector_type(4))) float f32x4;    // MFMA acc

// upper-triangle tile lookup (rt <= ct)
__device__ const unsigned char RT_[36] =
    {0,0,0,0,0,0,0,0, 1,1,1,1,1,1,1, 2,2,2,2,2,2, 3,3,3,3,3, 4,4,4,4, 5,5,5, 6,6, 7};
__device__ const unsigned char CT_[36] =
    {0,1,2,3,4,5,6,7, 1,2,3,4,5,6,7, 2,3,4,5,6,7, 3,4,5,6,7, 4,5,6,7, 5,6,7, 6,7, 7};

__device__ __forceinline__ unsigned short bf16r(float f) {   // RNE f32->bf16
    unsigned int u = __float_as_uint(f);
    u += 0x7fffu + ((u >> 16) & 1u);
    return (unsigned short)(u >> 16);
}

// ================= prep: zero | resize | norm (block-range specialized) ======
__global__ __launch_bounds__(256) void k_prep(const float* __restrict__ fo_in,
                                              const float* __restrict__ fsem,
                                              float* __restrict__ ws) {
    const int bid = blockIdx.x, tid = threadIdx.x;
    if (bid < 19) {
        int i = bid * 256 + tid;
        if (i < ZERO_COUNT) ws[ZERO_START + i] = 0.f;
    } else if (bid < 103) {
        const int bc = bid - 19;
        const float* im = fo_in + bc * 4096;
        for (int p = tid; p < 1024; p += 256) {
            const int oy = p >> 5, ox = p & 31;
            const float R = 63.0f / 31.0f;      // same f32 arithmetic as JAX ref
            float sy = oy * R, sx = ox * R;
            int y0 = (int)sy, x0 = (int)sx;
            int y1 = min(y0 + 1, 63), x1 = min(x0 + 1, 63);
            float wy = sy - (float)y0, wx = sx - (float)x0;
            float v00 = im[y0 * 64 + x0], v01 = im[y0 * 64 + x1];
            float v10 = im[y1 * 64 + x0], v11 = im[y1 * 64 + x1];
            float top = v00 * (1.f - wx) + v01 * wx;
            float bot = v10 * (1.f - wx) + v11 * wx;
            ws[OFF_FO + bc * NPIX + p] = top * (1.f - wy) + bot * wy;
        }
    } else {
        const int blk = bid - 103;
        const int b = blk >> 4, pg = blk & 15;
        const int p0 = pg * 64;
        const int pi = tid & 63, cg = tid >> 6;
        float s = 0.f;
        for (int c = cg; c < 256; c += 4) {
            float v = fsem[(b * 256 + c) * 1024 + p0 + pi];
            s += v * v;
        }
        __shared__ float red[4][64];
        red[cg][pi] = s;
        __syncthreads();
        if (tid < 64) {
            float t = red[0][tid] + red[1][tid] + red[2][tid] + red[3][tid];
            ws[OFF_INVN + b * 1024 + p0 + tid] = 1.f / fmaxf(sqrtf(t), 1e-12f);
        }
    }
}

// ================= main: MFMA gram || levelset ===============================
// gram = tau tile via bf16 MFMA (m97 gemm_bt pattern: C=F·F^T, both operands
// [row][k] slabs, frag: row=lane&15, k=(lane>>4)*8+j; C: col=lane&15,
// row=(lane>>4)*4+reg [m89]). Frees the 13.7us fp32-VALU gram floor that
// R3-R9 showed was the fused kernel's invariant cost.
__device__ __forceinline__ void acc_px(float4 o, float4 ta, float4 tb, float4 tc,
                                       float& dn, float& n0, float& n1, float& n2,
                                       float& q0, float& q1, float& q2) {
    dn += o.x + o.y + o.z + o.w;
    n0 += ta.x*o.x + ta.y*o.y + ta.z*o.z + ta.w*o.w;
    q0 += ta.x*ta.x*o.x + ta.y*ta.y*o.y + ta.z*ta.z*o.z + ta.w*ta.w*o.w;
    n1 += tb.x*o.x + tb.y*o.y + tb.z*o.z + tb.w*o.w;
    q1 += tb.x*tb.x*o.x + tb.y*tb.y*o.y + tb.z*tb.z*o.z + tb.w*tb.w*o.w;
    n2 += tc.x*o.x + tc.y*o.y + tc.z*o.z + tc.w*o.w;
    q2 += tc.x*tc.x*o.x + tc.y*tc.y*o.y + tc.z*tc.z*o.z + tc.w*tc.w*o.w;
}

#define LSTR 40   // LDS row stride in bf16 (80 B: 16B-aligned frag reads)

__global__ __launch_bounds__(256) void k_main(const float* __restrict__ outp,
                                              const float* __restrict__ tgt,
                                              const float* __restrict__ fsem,
                                              float* __restrict__ ws) {
    __shared__ __align__(16) char smem[20480];
    const int tid = threadIdx.x;

    if (blockIdx.x < N_GRAM_BLK) {
        unsigned short* Asub = (unsigned short*)smem;            // 128*40*2 = 10240
        unsigned short* Bsub = (unsigned short*)(smem + 10240);  // 10240
        const int bid = blockIdx.x;
        const int b = bid / 36, t = bid % 36;
        const int rt = RT_[t], ct = CT_[t];
        const bool diag = (rt == ct);
        const int r0 = rt * 128, c0 = ct * 128;

        const int ch_l = tid & 31, pxg = tid >> 5;     // stage assignment
        const int w = tid >> 6, l = tid & 63;          // mfma assignment
        const int wr = (w >> 1) * 64, wc = (w & 1) * 64;
        const int lr = l & 15, lg = l >> 4;

        f32x4 acc[4][4];
        #pragma unroll
        for (int i = 0; i < 4; ++i)
            #pragma unroll
            for (int j = 0; j < 4; ++j) acc[i][j] = (f32x4){0.f, 0.f, 0.f, 0.f};

        for (int kk = 0; kk < 8; ++kk) {
            __syncthreads();   // protect previous iter's reads
            // stage [128 px][32 ch] of A(r0) and B(c0), bf16, px-contiguous gl reads
            const float* fb = fsem + (size_t)(b * 256 + kk * 32 + ch_l) * 1024;
            #pragma unroll
            for (int q = 0; q < 4; ++q) {
                float4 va = *(const float4*)(fb + r0 + pxg * 16 + q * 4);
                float4 vb = *(const float4*)(fb + c0 + pxg * 16 + q * 4);
                const int px = pxg * 16 + q * 4;
                Asub[(px + 0) * LSTR + ch_l] = bf16r(va.x);
                Asub[(px + 1) * LSTR + ch_l] = bf16r(va.y);
                Asub[(px + 2) * LSTR + ch_l] = bf16r(va.z);
                Asub[(px + 3) * LSTR + ch_l] = bf16r(va.w);
                Bsub[(px + 0) * LSTR + ch_l] = bf16r(vb.x);
                Bsub[(px + 1) * LSTR + ch_l] = bf16r(vb.y);
                Bsub[(px + 2) * LSTR + ch_l] = bf16r(vb.z);
                Bsub[(px + 3) * LSTR + ch_l] = bf16r(vb.w);
            }
            __syncthreads();
            short8 a8[4], b8[4];
            #pragma unroll
            for (int fr = 0; fr < 4; ++fr)
                a8[fr] = *(const short8*)(Asub + (wr + fr * 16 + lr) * LSTR + lg * 8);
            #pragma unroll
            for (int fc = 0; fc < 4; ++fc)
                b8[fc] = *(const short8*)(Bsub + (wc + fc * 16 + lr) * LSTR + lg * 8);
            #pragma unroll
            for (int fr = 0; fr < 4; ++fr)
                #pragma unroll
                for (int fc = 0; fc < 4; ++fc)
                    acc[fr][fc] = __builtin_amdgcn_mfma_f32_16x16x32_bf16(
                        a8[fr], b8[fc], acc[fr][fc], 0, 0, 0);
        }

        // scale in place: v = relu(dot) * invn_row * invn_col
        float ir[4][4], ic[4];
        #pragma unroll
        for (int fr = 0; fr < 4; ++fr)
            #pragma unroll
            for (int rg = 0; rg < 4; ++rg)
                ir[fr][rg] = ws[OFF_INVN + b * 1024 + r0 + wr + fr * 16 + lg * 4 + rg];
        #pragma unroll
        for (int fc = 0; fc < 4; ++fc)
            ic[fc] = ws[OFF_INVN + b * 1024 + c0 + wc + fc * 16 + lr];
        #pragma unroll
        for (int fr = 0; fr < 4; ++fr)
            #pragma unroll
            for (int fc = 0; fc < 4; ++fc)
                #pragma unroll
                for (int rg = 0; rg < 4; ++rg)
                    acc[fr][fc][rg] = fmaxf(acc[fr][fc][rg], 0.f) * ir[fr][rg] * ic[fc];

        // row-side: sums over 32-col halves + row max (exclusive -> plain store)
        #pragma unroll
        for (int fr = 0; fr < 4; ++fr)
            #pragma unroll
            for (int rg = 0; rg < 4; ++rg) {
                float v0 = acc[fr][0][rg] + acc[fr][1][rg];
                float v1 = acc[fr][2][rg] + acc[fr][3][rg];
                float m  = fmaxf(fmaxf(acc[fr][0][rg], acc[fr][1][rg]),
                                 fmaxf(acc[fr][2][rg], acc[fr][3][rg]));
                #pragma unroll
                for (int msk = 1; msk < 16; msk <<= 1) {
                    v0 += __shfl_xor(v0, msk);
                    v1 += __shfl_xor(v1, msk);
                    m = fmaxf(m, __shfl_xor(m, msk));
                }
                if (lr == 0) {
                    const int row = r0 + wr + fr * 16 + lg * 4 + rg;
                    float* g = ws + OFF_GSUM + (size_t)(b * 1024 + row) * 32
                             + ct * 4 + (w & 1) * 2;
                    g[0] = v0; g[1] = v1;
                    atomicMax((int*)&ws[OFF_RMAX + b * 1024 + row], __float_as_int(m));
                }
            }
        // col-side mirror (rt<ct): sums over 32-row halves + col max
        if (!diag) {
            #pragma unroll
            for (int fc = 0; fc < 4; ++fc) {
                float c0s = 0.f, c1s = 0.f, cm = 0.f;
                #pragma unroll
                for (int rg = 0; rg < 4; ++rg) {
                    c0s += acc[0][fc][rg] + acc[1][fc][rg];
                    c1s += acc[2][fc][rg] + acc[3][fc][rg];
                    cm = fmaxf(cm, fmaxf(fmaxf(acc[0][fc][rg], acc[1][fc][rg]),
                                         fmaxf(acc[2][fc][rg], acc[3][fc][rg])));
                }
                #pragma unroll
                for (int msk = 16; msk < 64; msk <<= 1) {
                    c0s += __shfl_xor(c0s, msk);
                    c1s += __shfl_xor(c1s, msk);
                    cm = fmaxf(cm, __shfl_xor(cm, msk));
                }
                if (lg == 0) {
                    const int col = c0 + wc + fc * 16 + lr;
                    float* g = ws + OFF_GSUM + (size_t)(b * 1024 + col) * 32
                             + rt * 4 + (w >> 1) * 2;
                    g[0] = c0s; g[1] = c1s;
                    atomicMax((int*)&ws[OFF_RMAX + b * 1024 + col], __float_as_int(cm));
                }
            }
        }
    } else {
        // -------- levelset partials (R8 structure, unchanged) ----------------
        float (*red)[7] = (float (*)[7])smem;
        const int blk = blockIdx.x - N_GRAM_BLK;
        const int slice = blk & 31, bc = blk >> 5;
        const int b = bc / 21;
        const float4* o4 = (const float4*)(outp + (size_t)bc * HWSZ + slice * 8192);
        const float4* t4 = (const float4*)(tgt + (size_t)b * (3 * HWSZ) + slice * 8192);
        float dn = 0, n0 = 0, n1 = 0, n2 = 0, q0 = 0, q1 = 0, q2 = 0;
        #pragma unroll
        for (int half = 0; half < 2; ++half) {
            float4 o[4], ta[4], tb[4], tc[4];
            #pragma unroll
            for (int j = 0; j < 4; ++j) {
                const int i = tid + (half * 4 + j) * 256;
                o[j]  = o4[i];
                ta[j] = t4[i];
                tb[j] = t4[i + 65536];    // +262144 floats
                tc[j] = t4[i + 131072];
            }
            #pragma unroll
            for (int j = 0; j < 4; ++j)
                acc_px(o[j], ta[j], tb[j], tc[j], dn, n0, n1, n2, q0, q1, q2);
        }
        float vals[7] = {n0, n1, n2, q0, q1, q2, dn};
        #pragma unroll
        for (int j = 0; j < 7; ++j) {
            float v = vals[j];
            #pragma unroll
            for (int off = 32; off; off >>= 1) v += __shfl_xor(v, off);
            if ((tid & 63) == 0) red[tid >> 6][j] = v;
        }
        __syncthreads();
        if (tid < 7) {
            float s = red[0][tid] + red[1][tid] + red[2][tid] + red[3][tid];
            atomicAdd(&ws[OFF_LS + bc * 7 + tid], s);
        }
    }
}

// ================= final TV contraction: sum A[b,c,r,k]*t[b,r,k] =============
__global__ __launch_bounds__(256) void k_tv(const float* __restrict__ ws,
                                            float* __restrict__ acc_out) {
    const int bc = blockIdx.y;
    const int b = bc / 21;
    const int tid = threadIdx.x;
    __shared__ float4 fo4[256];
    const float4* src = (const float4*)(ws + OFF_FO + bc * NPIX);
    fo4[tid] = src[tid];
    __syncthreads();
    const int r = blockIdx.x * 256 + tid;
    const float v = ((const float*)fo4)[r];
    float ak[32];
    #pragma unroll
    for (int k = 0; k < 32; ++k) ak[k] = 0.f;
    #pragma unroll 4
    for (int h = 0; h < 32; ++h) {
        #pragma unroll
        for (int k4 = 0; k4 < 8; ++k4) {
            float4 f = fo4[h * 8 + k4];
            ak[k4 * 4 + 0] += fabsf(v - f.x);
            ak[k4 * 4 + 1] += fabsf(v - f.y);
            ak[k4 * 4 + 2] += fabsf(v - f.z);
            ak[k4 * 4 + 3] += fabsf(v - f.w);
        }
    }
    const float rm = ws[OFF_RMAX + b * 1024 + r];
    const float inv = 1.f / (rm + 1e-5f);
    const float* t = ws + OFF_GSUM + (b * 1024 + r) * 32;
    float dot = 0.f;
    #pragma unroll
    for (int k = 0; k < 32; ++k) dot += ak[k] * t[k];
    float part = dot * inv;
    #pragma unroll
    for (int off = 32; off; off >>= 1) part += __shfl_xor(part, off);
    __shared__ float red[4];
    if ((tid & 63) == 0) red[tid >> 6] = part;
    __syncthreads();
    if (tid == 0) atomicAdd(acc_out, red[0] + red[1] + red[2] + red[3]);
}

// ================= combine to 3 outputs ======================================
__global__ void k_combine(const float* __restrict__ ws, float* __restrict__ out) {
    const int tid = threadIdx.x;   // 128
    float v = 0.f;
    if (tid < NBC) {
        const float* p = ws + OFF_LS + tid * 7;
        float den = p[6];
        v = (p[3] + p[4] + p[5]) - (p[0]*p[0] + p[1]*p[1] + p[2]*p[2]) / den;
    }
    #pragma unroll
    for (int off = 32; off; off >>= 1) v += __shfl_xor(v, off);
    __shared__ float red[2];
    if ((tid & 63) == 0) red[tid >> 6] = v;
    __syncthreads();
    if (tid == 0) {
        float lsv = (red[0] + red[1]) * 0.25f;     // / B
        float tvv = ws[OFF_ACC] * 0.25f;           // / B
        out[0] = lsv * BETA_F;
        out[1] = tvv * LAMBDA_F * BETA_F;
        out[2] = (lsv + tvv * LAMBDA_F) * BETA_F;
    }
}

extern "C" void kernel_launch(void* const* d_in, const int* in_sizes, int n_in,
                              void* d_out, int out_size, void* d_ws, size_t ws_size,
                              hipStream_t stream) {
    const float* output   = (const float*)d_in[0];   // (4,21,512,512)
    const float* target   = (const float*)d_in[1];   // (4,3,512,512)
    const float* f_sem    = (const float*)d_in[2];   // (4,256,32,32)
    const float* f_output = (const float*)d_in[3];   // (4,21,64,64)
    // d_in[4] = use_NonLocal_TV, fixed to 1 by setup_inputs
    float* ws  = (float*)d_ws;
    float* out = (float*)d_out;

    hipLaunchKernelGGL(k_prep,    dim3(167),             dim3(256), 0, stream, f_output, f_sem, ws);
    hipLaunchKernelGGL(k_main,    dim3(N_GRAM_BLK+2688), dim3(256), 0, stream, output, target, f_sem, ws);
    hipLaunchKernelGGL(k_tv,      dim3(4, 84),           dim3(256), 0, stream, ws, ws + OFF_ACC);
    hipLaunchKernelGGL(k_combine, dim3(1),               dim3(128), 0, stream, ws, out);
}